// Round 8
// baseline (114.493 us; speedup 1.0000x reference)
//
#include <hip/hip_runtime.h>
#include <hip/hip_bf16.h>
#include <math.h>

#define DM 64
#define NH 4
#define HD 16
#define BATCH 16
#define TSEQ 1024

typedef short bf16x8 __attribute__((ext_vector_type(8)));
typedef float f32x16 __attribute__((ext_vector_type(16)));

static __device__ inline short f2bf(float x) {
    __hip_bfloat16 h = __float2bfloat16(x);
    return __builtin_bit_cast(short, h);
}
static __device__ inline float bf2f(short s) {
    __hip_bfloat16 h = __builtin_bit_cast(__hip_bfloat16, s);
    return __bfloat162float(h);
}
static __device__ inline unsigned pack2bf(float a, float b) {
    const unsigned lo = (unsigned short)f2bf(a);
    const unsigned hi = (unsigned short)f2bf(b);
    return lo | (hi << 16);
}

// ---------------- Kernel 1: fused Q/K/V projections -> bf16 ---------------
// 1D grid 384, XCD-swizzled: rowblock = (slot&3)*8 + xcd so all 12 parts
// re-reading one 512-row enc/x range hit the SAME XCD's L2 (round-robin
// dispatch maps bid%8 -> XCD). thread = 2 rows x 16 cols; W slice in LDS.
// parts 0-3: q (scaled 0.25*log2e, hi/lo), 4-7: k (hi/lo), 8-11: v -> TILED
// vtt[b][h][kb][d][kw] with mask folded in (v *= mask, row d=16 = maskbit).
__global__ __launch_bounds__(256) void proj_kernel(
    const float* __restrict__ x, const float* __restrict__ enc,
    const float* __restrict__ Wkv, const float* __restrict__ bkv,
    const float* __restrict__ Wq,  const float* __restrict__ bq,
    const int* __restrict__ mask,
    short* __restrict__ qhi, short* __restrict__ qlo,
    short* __restrict__ khi, short* __restrict__ klo,
    short* __restrict__ vtt)
{
    const int t = threadIdx.x;
    const int bid  = blockIdx.x;
    const int xcd  = bid & 7;
    const int slot = bid >> 3;                    // 0..47
    const int rowblock = (slot & 3) * 8 + xcd;    // 0..31 -> fixed XCD per row-range
    const int part     = slot >> 2;               // 0..11
    const int r0 = rowblock * 512 + t;            // rows r0, r0+256

    const float* in; const float* W; const float* bias; int cb, ldw;
    if (part < 4)      { in = x;   W = Wq;  ldw = 64;  cb = part*16;          bias = bq;  }
    else if (part < 8) { in = enc; W = Wkv; ldw = 128; cb = (part-4)*16;      bias = bkv; }
    else               { in = enc; W = Wkv; ldw = 128; cb = 64 + (part-8)*16; bias = bkv; }

    const float4* row0 = (const float4*)(in + (size_t)r0 * 64);
    const float4* row1 = (const float4*)(in + (size_t)(r0 + 256) * 64);

    // first x chunk in flight before the staging barrier
    float4 xc[2][4];
    #pragma unroll
    for (int v4 = 0; v4 < 4; ++v4) { xc[0][v4] = row0[v4]; xc[1][v4] = row1[v4]; }

    __shared__ float wsl[64][16];
    #pragma unroll
    for (int idx = t; idx < 1024; idx += 256)
        wsl[idx >> 4][idx & 15] = W[(idx >> 4)*ldw + cb + (idx & 15)];
    __syncthreads();

    float acc[2][16];
    #pragma unroll
    for (int j = 0; j < 16; ++j) { float bj = bias[cb + j]; acc[0][j] = bj; acc[1][j] = bj; }

    for (int kc = 0; kc < 4; ++kc) {
        float4 xn[2][4];
        if (kc < 3) {
            #pragma unroll
            for (int v4 = 0; v4 < 4; ++v4) {
                xn[0][v4] = row0[(kc+1)*4 + v4];
                xn[1][v4] = row1[(kc+1)*4 + v4];
            }
        }
        #pragma unroll
        for (int i = 0; i < 16; ++i) {
            const int k = kc*16 + i;
            const float4 w0 = ((const float4*)&wsl[k][0])[0];
            const float4 w1 = ((const float4*)&wsl[k][0])[1];
            const float4 w2 = ((const float4*)&wsl[k][0])[2];
            const float4 w3 = ((const float4*)&wsl[k][0])[3];
            #pragma unroll
            for (int rr = 0; rr < 2; ++rr) {
                const float xv = ((const float*)&xc[rr][i >> 2])[i & 3];
                acc[rr][0]  += xv*w0.x; acc[rr][1]  += xv*w0.y; acc[rr][2]  += xv*w0.z; acc[rr][3]  += xv*w0.w;
                acc[rr][4]  += xv*w1.x; acc[rr][5]  += xv*w1.y; acc[rr][6]  += xv*w1.z; acc[rr][7]  += xv*w1.w;
                acc[rr][8]  += xv*w2.x; acc[rr][9]  += xv*w2.y; acc[rr][10] += xv*w2.z; acc[rr][11] += xv*w2.w;
                acc[rr][12] += xv*w3.x; acc[rr][13] += xv*w3.y; acc[rr][14] += xv*w3.z; acc[rr][15] += xv*w3.w;
            }
        }
        if (kc < 3) {
            #pragma unroll
            for (int v4 = 0; v4 < 4; ++v4) { xc[0][v4] = xn[0][v4]; xc[1][v4] = xn[1][v4]; }
        }
    }

    #pragma unroll
    for (int rr = 0; rr < 2; ++rr) {
        const int r = r0 + rr*256;
        const int b = r >> 10, trow = r & 1023;
        if (part < 8) {
            const float scale = (part < 4) ? 0.36067376022224085f : 1.0f;  // 0.25*log2(e)
            short* dh = (part < 4) ? qhi : khi;
            short* dl = (part < 4) ? qlo : klo;
            const int h = (part < 4) ? part : (part - 4);
            bf16x8 h0, h1, l0, l1;
            #pragma unroll
            for (int j = 0; j < 16; ++j) {
                float vf = acc[rr][j] * scale;
                short hb = f2bf(vf);
                short lb = f2bf(vf - bf2f(hb));
                if (j < 8) { h0[j] = hb; l0[j] = lb; }
                else       { h1[j-8] = hb; l1[j-8] = lb; }
            }
            size_t off = (((size_t)(b*NH + h))*TSEQ + trow)*HD;
            *(bf16x8*)(dh + off)     = h0;
            *(bf16x8*)(dh + off + 8) = h1;
            *(bf16x8*)(dl + off)     = l0;
            *(bf16x8*)(dl + off + 8) = l1;
        } else {
            // vtt[b][h][kb=key>>5][d(0-15 data,16 maskbit,17-31 unused)][kw=key&31]
            const int h = part - 8;
            const float mb = (mask[b*TSEQ + trow] != 0) ? 1.0f : 0.0f;
            short* tile = vtt + ((size_t)(b*NH + h))*32768 + (size_t)(trow >> 5)*1024;
            const int kw = trow & 31;
            #pragma unroll
            for (int j = 0; j < 16; ++j)
                tile[j*32 + kw] = f2bf(acc[rr][j] * mb);
            tile[16*32 + kw] = (mb != 0.0f) ? (short)0x3F80 : (short)0;
        }
    }
}

// ---------------- Kernel 2: MFMA flash attention + Wproj epilogue ----------
// 1D grid 512, XCD-swizzled: b = (slot&1)*8 + xcd so all 32 q-tile blocks
// of a batch land on ONE XCD (round-robin bid%8 -> XCD). Per-XCD working
// set = 2 batches x 0.75 MB = 1.5 MB < 4 MB L2 -> K/V re-reads are L2 hits
// (was: scattered across XCDs -> L3-bound at ~19 TB/s).
// Per 32-key step (512 thr = 8 waves = 4 heads x 2 key-halves):
//   S^T[key][q] = 3x mfma(A=K hi/lo, B=Q hi/lo)  (P exits rows=keys)
//   p = exp2(S^T); pack bf16; 4x shfl_xor(,32) builds P^T frags in-register
//   ctx^T += 2x mfma(A = V^T tiled (mask folded, row16 = maskbit -> free l))
// Partials combine in LDS; epilogue normalizes + applies Wproj.
__global__ __launch_bounds__(512) void attn_kernel(
    const short* __restrict__ qhi, const short* __restrict__ qlo,
    const short* __restrict__ khi, const short* __restrict__ klo,
    const short* __restrict__ vtt,
    const float* __restrict__ Wproj, const float* __restrict__ bproj,
    float* __restrict__ out)
{
    const int tid  = threadIdx.x;
    const int lane = tid & 63;
    const int wid  = __builtin_amdgcn_readfirstlane(tid >> 6);  // 0..7
    const int h  = wid & 3;
    const int ks = wid >> 2;          // key half
    const int bid  = blockIdx.x;
    const int xcd  = bid & 7;
    const int slot = bid >> 3;                 // 0..63
    const int b    = (slot & 1) * 8 + xcd;     // batch -> fixed XCD
    const int qbase = (slot >> 1) * 32;        // q-tile 0..31
    const int l31 = lane & 31;
    const bool hf = (lane >> 5) != 0;

    __shared__ float Cbuf[2][32][67];    // [ks][q][4 heads x 16 d]; stride 67
    __shared__ float Lbuf[2][NH][32];

    // Q as MFMA B-operand: B[k=hf*8+j][n=q=l31]
    const size_t qoff = (((size_t)(b*NH + h))*TSEQ + qbase + l31)*HD + (hf ? 8 : 0);
    const bf16x8 qBh = *(const bf16x8*)(qhi + qoff);
    const bf16x8 qBl = *(const bf16x8*)(qlo + qoff);

    const short* khb = khi + (((size_t)(b*NH + h))*TSEQ + ks*512)*HD;
    const short* klb = klo + (((size_t)(b*NH + h))*TSEQ + ks*512)*HD;
    const short* vtb = vtt + ((size_t)(b*NH + h))*32768 + (size_t)ks*16384;

    f32x16 Cacc;
    #pragma unroll
    for (int i = 0; i < 16; ++i) Cacc[i] = 0.f;

    for (int step = 0; step < 16; ++step) {
        const int ko = step * 32;
        // K as MFMA A-operand: A[m=key=l31][k=hf*8+j] (1 KB contiguous/wave)
        const bf16x8 kAh = *(const bf16x8*)(khb + (size_t)(ko + l31)*HD + (hf ? 8 : 0));
        const bf16x8 kAl = *(const bf16x8*)(klb + (size_t)(ko + l31)*HD + (hf ? 8 : 0));
        // V^T as MFMA A-operand from tiled vtt: A[m=d=l31][k=kw]; lane
        // stride 64 B -> wave consumes the 2 KB tile once, fully coalesced
        const short* tile = vtb + (size_t)step * 1024;
        const bf16x8 vA0 = *(const bf16x8*)(tile + l31*32 + (hf ? 8 : 0));       // keys 0-15
        const bf16x8 vA1 = *(const bf16x8*)(tile + l31*32 + 16 + (hf ? 8 : 0));  // keys 16-31

        f32x16 S;   // S^T: C-layout lane holds col q=l31, rows=keys
        #pragma unroll
        for (int i = 0; i < 16; ++i) S[i] = 0.f;
        S = __builtin_amdgcn_mfma_f32_32x32x16_bf16(kAh, qBh, S, 0, 0, 0);
        S = __builtin_amdgcn_mfma_f32_32x32x16_bf16(kAh, qBl, S, 0, 0, 0);
        S = __builtin_amdgcn_mfma_f32_32x32x16_bf16(kAl, qBh, S, 0, 0, 0);

        float p[16];
        #pragma unroll
        for (int i = 0; i < 16; ++i) p[i] = __builtin_amdgcn_exp2f(S[i]);

        // pack pairs (rows 2i,2i+1) to bf16x2
        unsigned pk[8];
        #pragma unroll
        for (int i = 0; i < 8; ++i) pk[i] = pack2bf(p[2*i], p[2*i+1]);

        // exchange across lane^32:
        //   hf=0 lane needs partner pk0,pk1 (frag1) and pk4,pk5 (frag2)
        //   hf=1 lane needs partner pk2,pk3 (frag1) and pk6,pk7 (frag2)
        const unsigned sA = hf ? pk[0] : pk[2];
        const unsigned sB = hf ? pk[1] : pk[3];
        const unsigned sC = hf ? pk[4] : pk[6];
        const unsigned sD = hf ? pk[5] : pk[7];
        const unsigned rA = (unsigned)__shfl_xor((int)sA, 32);
        const unsigned rB = (unsigned)__shfl_xor((int)sB, 32);
        const unsigned rC = (unsigned)__shfl_xor((int)sC, 32);
        const unsigned rD = (unsigned)__shfl_xor((int)sD, 32);

        // assemble P^T B-frags: B[k=hf*8+j][n=q=l31]
        int4 b1, b2;
        b1.x = hf ? (int)rA    : (int)pk[0];   // k rows 0-1 / 8-9
        b1.y = hf ? (int)rB    : (int)pk[1];   // 2-3 / 10-11
        b1.z = hf ? (int)pk[2] : (int)rA;      // 4-5 / 12-13
        b1.w = hf ? (int)pk[3] : (int)rB;      // 6-7 / 14-15
        b2.x = hf ? (int)rC    : (int)pk[4];
        b2.y = hf ? (int)rD    : (int)pk[5];
        b2.z = hf ? (int)pk[6] : (int)rC;
        b2.w = hf ? (int)pk[7] : (int)rD;
        const bf16x8 pB0 = __builtin_bit_cast(bf16x8, b1);
        const bf16x8 pB1 = __builtin_bit_cast(bf16x8, b2);

        Cacc = __builtin_amdgcn_mfma_f32_32x32x16_bf16(vA0, pB0, Cacc, 0, 0, 0);
        Cacc = __builtin_amdgcn_mfma_f32_32x32x16_bf16(vA1, pB1, Cacc, 0, 0, 0);
    }

    // Cacc = ctx^T[d][q]: lane holds col q=l31, rows d=(r&3)+8*(r>>2)+4*hf.
    // r=0..7 -> d in {0-3,8-11}+4*hf; r=8, hf=0 -> d=16 = l (maskbit row).
    #pragma unroll
    for (int r = 0; r < 8; ++r) {
        const int d = (r & 3) + 8*(r >> 2) + (hf ? 4 : 0);
        Cbuf[ks][l31][h*HD + d] = Cacc[r];
    }
    if (!hf) Lbuf[ks][h][l31] = Cacc[8];
    __syncthreads();

    // epilogue: thread = (q=tid>>4, 4 out cols); combine key-halves,
    // normalize per head, apply Wproj + bproj
    const int q   = tid >> 4;        // 0..31
    const int cbo = (tid & 15) * 4;  // 0..60
    float linv[NH];
    #pragma unroll
    for (int hh = 0; hh < NH; ++hh)
        linv[hh] = 1.0f / (Lbuf[0][hh][q] + Lbuf[1][hh][q]);

    float o0 = bproj[cbo], o1 = bproj[cbo+1], o2 = bproj[cbo+2], o3 = bproj[cbo+3];
    #pragma unroll
    for (int i = 0; i < 64; ++i) {
        const float cv = (Cbuf[0][q][i] + Cbuf[1][q][i]) * linv[i >> 4];
        const float4 wr = *(const float4*)(Wproj + i*DM + cbo);
        o0 += cv*wr.x; o1 += cv*wr.y; o2 += cv*wr.z; o3 += cv*wr.w;
    }
    float4 st; st.x = o0; st.y = o1; st.z = o2; st.w = o3;
    *(float4*)(out + ((size_t)b*TSEQ + qbase + q)*DM + cbo) = st;
}

extern "C" void kernel_launch(void* const* d_in, const int* in_sizes, int n_in,
                              void* d_out, int out_size, void* d_ws, size_t ws_size,
                              hipStream_t stream) {
    const float* x     = (const float*)d_in[0];
    const float* enc   = (const float*)d_in[1];
    const int*   mask  = (const int*)  d_in[2];
    const float* Wkv   = (const float*)d_in[3];
    const float* bkv   = (const float*)d_in[4];
    const float* Wq    = (const float*)d_in[5];
    const float* bq    = (const float*)d_in[6];
    const float* Wproj = (const float*)d_in[7];
    const float* bproj = (const float*)d_in[8];
    float* out = (float*)d_out;

    // ws: qhi,qlo,khi,klo 2MB each + vtt tiled (32 d-rows) 4MB = 12MB
    const size_t SZ = (size_t)BATCH*NH*TSEQ*HD;
    short* qhi = (short*)d_ws;
    short* qlo = qhi + SZ;
    short* khi = qlo + SZ;
    short* klo = khi + SZ;
    short* vtt = klo + SZ;   // BATCH*NH*32768 shorts

    proj_kernel<<<dim3(384), dim3(256), 0, stream>>>(
        x, enc, Wkv, bkv, Wq, bq, mask, qhi, qlo, khi, klo, vtt);
    attn_kernel<<<dim3(512), dim3(512), 0, stream>>>(
        qhi, qlo, khi, klo, vtt, Wproj, bproj, out);
}

// Round 9
// 114.038 us; speedup vs baseline: 1.0040x; 1.0040x over previous
//
#include <hip/hip_runtime.h>
#include <hip/hip_bf16.h>
#include <math.h>

#define DM 64
#define NH 4
#define HD 16
#define BATCH 16
#define TSEQ 1024

typedef short bf16x8 __attribute__((ext_vector_type(8)));
typedef float f32x16 __attribute__((ext_vector_type(16)));

// fast RNE float->bf16 (finite inputs only: no NaN/inf path).
static __device__ inline unsigned bfround(float x) {
    unsigned u = __builtin_bit_cast(unsigned, x);
    return u + 0x7fffu + ((u >> 16) & 1u);     // rounded bits; bf16 = [31:16]
}
static __device__ inline short f2bf(float x) {
    return (short)(bfround(x) >> 16);
}
static __device__ inline float bf2f(short s) {
    unsigned u = ((unsigned)(unsigned short)s) << 16;
    float f = __builtin_bit_cast(float, u);
    return f;
}
// pack two finite floats to bf16x2 (a->low, b->high), ~5 VALU
static __device__ inline unsigned pack2bf(float a, float b) {
    return (bfround(a) >> 16) | (bfround(b) & 0xffff0000u);
}

// ---------------- Kernel 1: fused Q/K/V projections -> bf16 ---------------
// grid = (64 rowblocks, 12 parts) = 768 blocks (3 blocks/CU), 256 thr,
// thread = 1 row x 16 cols (one head). parts 0-3: q (scaled 0.25*log2e,
// hi/lo), 4-7: k (hi/lo), 8-11: v -> TILED vtt[b][h][kb][d][kw] with mask
// folded in (v *= mask, row d=16 = maskbit). W slice staged in LDS.
__global__ __launch_bounds__(256) void proj_kernel(
    const float* __restrict__ x, const float* __restrict__ enc,
    const float* __restrict__ Wkv, const float* __restrict__ bkv,
    const float* __restrict__ Wq,  const float* __restrict__ bq,
    const int* __restrict__ mask,
    short* __restrict__ qhi, short* __restrict__ qlo,
    short* __restrict__ khi, short* __restrict__ klo,
    short* __restrict__ vtt)
{
    const int t = threadIdx.x;
    const int part = blockIdx.y;          // 0..11
    const int r = blockIdx.x * 256 + t;   // global row 0..16383
    const int b = r >> 10, trow = r & 1023;

    const float* in; const float* W; const float* bias; int cb, ldw;
    if (part < 4)      { in = x;   W = Wq;  ldw = 64;  cb = part*16;          bias = bq;  }
    else if (part < 8) { in = enc; W = Wkv; ldw = 128; cb = (part-4)*16;      bias = bkv; }
    else               { in = enc; W = Wkv; ldw = 128; cb = 64 + (part-8)*16; bias = bkv; }

    __shared__ float wsl[64][16];
    for (int idx = t; idx < 1024; idx += 256)
        wsl[idx >> 4][idx & 15] = W[(idx >> 4)*ldw + cb + (idx & 15)];

    // full input row up front (latency overlaps the staging barrier)
    float4 xr[16];
    const float4* inrow = (const float4*)(in + (size_t)r * 64);
    #pragma unroll
    for (int i = 0; i < 16; ++i) xr[i] = inrow[i];
    __syncthreads();

    float acc[16];
    #pragma unroll
    for (int j = 0; j < 16; ++j) acc[j] = bias[cb + j];
    #pragma unroll
    for (int k = 0; k < 64; ++k) {
        const float xv = ((const float*)xr)[k];
        const float4 w0 = ((const float4*)&wsl[k][0])[0];
        const float4 w1 = ((const float4*)&wsl[k][0])[1];
        const float4 w2 = ((const float4*)&wsl[k][0])[2];
        const float4 w3 = ((const float4*)&wsl[k][0])[3];
        acc[0]  += xv*w0.x; acc[1]  += xv*w0.y; acc[2]  += xv*w0.z; acc[3]  += xv*w0.w;
        acc[4]  += xv*w1.x; acc[5]  += xv*w1.y; acc[6]  += xv*w1.z; acc[7]  += xv*w1.w;
        acc[8]  += xv*w2.x; acc[9]  += xv*w2.y; acc[10] += xv*w2.z; acc[11] += xv*w2.w;
        acc[12] += xv*w3.x; acc[13] += xv*w3.y; acc[14] += xv*w3.z; acc[15] += xv*w3.w;
    }

    if (part < 8) {
        // q: fold softmax scale AND log2(e) so attn uses exp2 directly
        const float scale = (part < 4) ? 0.36067376022224085f : 1.0f;
        short* dh = (part < 4) ? qhi : khi;
        short* dl = (part < 4) ? qlo : klo;
        const int h = (part < 4) ? part : (part - 4);
        bf16x8 h0, h1, l0, l1;
        #pragma unroll
        for (int j = 0; j < 16; ++j) {
            float vf = acc[j] * scale;
            short hb = f2bf(vf);
            short lb = f2bf(vf - bf2f(hb));
            if (j < 8) { h0[j] = hb; l0[j] = lb; }
            else       { h1[j-8] = hb; l1[j-8] = lb; }
        }
        size_t off = (((size_t)(b*NH + h))*TSEQ + trow)*HD;
        *(bf16x8*)(dh + off)     = h0;
        *(bf16x8*)(dh + off + 8) = h1;
        *(bf16x8*)(dl + off)     = l0;
        *(bf16x8*)(dl + off + 8) = l1;
    } else {
        // vtt[b][h][kb=key>>5][d(0-15 data,16 maskbit,17-31 unused)][kw=key&31]
        const int h = part - 8;
        const float mb = (mask[b*TSEQ + trow] != 0) ? 1.0f : 0.0f;
        short* tile = vtt + ((size_t)(b*NH + h))*32768 + (size_t)(trow >> 5)*1024;
        const int kw = trow & 31;
        #pragma unroll
        for (int j = 0; j < 16; ++j)
            tile[j*32 + kw] = f2bf(acc[j] * mb);
        tile[16*32 + kw] = (mb != 0.0f) ? (short)0x3F80 : (short)0;
    }
}

// ---------------- Kernel 2: MFMA flash attention + Wproj epilogue ----------
// 1D grid 512, XCD-swizzled (b pinned to one XCD). 512 thr = 8 waves =
// (4 heads x 2 key-halves). Per 32-key step:
//   S^T[key][q] = 3x mfma(A=K hi/lo, B=Q hi/lo)  (P exits rows=keys)
//   p = exp2(S^T); FAST bf16 pair-pack (5 VALU, finite-only RNE);
//   4x shfl_xor(,32) builds P^T B-frags in-register (no LDS round-trip)
//   ctx^T += 2x mfma(A = V^T tiled (coalesced, mask folded, row16 =
//   maskbit -> C[16][q] = l for free))
// Partials combine in LDS; epilogue normalizes + applies Wproj.
__global__ __launch_bounds__(512) void attn_kernel(
    const short* __restrict__ qhi, const short* __restrict__ qlo,
    const short* __restrict__ khi, const short* __restrict__ klo,
    const short* __restrict__ vtt,
    const float* __restrict__ Wproj, const float* __restrict__ bproj,
    float* __restrict__ out)
{
    const int tid  = threadIdx.x;
    const int lane = tid & 63;
    const int wid  = __builtin_amdgcn_readfirstlane(tid >> 6);  // 0..7
    const int h  = wid & 3;
    const int ks = wid >> 2;          // key half
    const int bid  = blockIdx.x;
    const int xcd  = bid & 7;
    const int slot = bid >> 3;                 // 0..63
    const int b    = (slot & 1) * 8 + xcd;     // batch -> fixed XCD
    const int qbase = (slot >> 1) * 32;        // q-tile 0..31
    const int l31 = lane & 31;
    const bool hf = (lane >> 5) != 0;

    __shared__ float Cbuf[2][32][67];    // [ks][q][4 heads x 16 d]; stride 67
    __shared__ float Lbuf[2][NH][32];

    // Q as MFMA B-operand: B[k=hf*8+j][n=q=l31]
    const size_t qoff = (((size_t)(b*NH + h))*TSEQ + qbase + l31)*HD + (hf ? 8 : 0);
    const bf16x8 qBh = *(const bf16x8*)(qhi + qoff);
    const bf16x8 qBl = *(const bf16x8*)(qlo + qoff);

    const short* khb = khi + (((size_t)(b*NH + h))*TSEQ + ks*512)*HD;
    const short* klb = klo + (((size_t)(b*NH + h))*TSEQ + ks*512)*HD;
    const short* vtb = vtt + ((size_t)(b*NH + h))*32768 + (size_t)ks*16384;

    f32x16 Cacc;
    #pragma unroll
    for (int i = 0; i < 16; ++i) Cacc[i] = 0.f;

    for (int step = 0; step < 16; ++step) {
        const int ko = step * 32;
        // K as MFMA A-operand: A[m=key=l31][k=hf*8+j] (1 KB contiguous/wave)
        const bf16x8 kAh = *(const bf16x8*)(khb + (size_t)(ko + l31)*HD + (hf ? 8 : 0));
        const bf16x8 kAl = *(const bf16x8*)(klb + (size_t)(ko + l31)*HD + (hf ? 8 : 0));
        // V^T as MFMA A-operand from tiled vtt: A[m=d=l31][k=kw]; lane
        // stride 64 B -> wave consumes the 2 KB tile once, fully coalesced
        const short* tile = vtb + (size_t)step * 1024;
        const bf16x8 vA0 = *(const bf16x8*)(tile + l31*32 + (hf ? 8 : 0));       // keys 0-15
        const bf16x8 vA1 = *(const bf16x8*)(tile + l31*32 + 16 + (hf ? 8 : 0));  // keys 16-31

        f32x16 S;   // S^T: C-layout lane holds col q=l31, rows=keys
        #pragma unroll
        for (int i = 0; i < 16; ++i) S[i] = 0.f;
        S = __builtin_amdgcn_mfma_f32_32x32x16_bf16(kAh, qBh, S, 0, 0, 0);
        S = __builtin_amdgcn_mfma_f32_32x32x16_bf16(kAh, qBl, S, 0, 0, 0);
        S = __builtin_amdgcn_mfma_f32_32x32x16_bf16(kAl, qBh, S, 0, 0, 0);

        float p[16];
        #pragma unroll
        for (int i = 0; i < 16; ++i) p[i] = __builtin_amdgcn_exp2f(S[i]);

        // pack pairs (rows 2i,2i+1) to bf16x2 — fast finite-only RNE
        unsigned pk[8];
        #pragma unroll
        for (int i = 0; i < 8; ++i) pk[i] = pack2bf(p[2*i], p[2*i+1]);

        // exchange across lane^32:
        //   hf=0 lane needs partner pk0,pk1 (frag1) and pk4,pk5 (frag2)
        //   hf=1 lane needs partner pk2,pk3 (frag1) and pk6,pk7 (frag2)
        const unsigned sA = hf ? pk[0] : pk[2];
        const unsigned sB = hf ? pk[1] : pk[3];
        const unsigned sC = hf ? pk[4] : pk[6];
        const unsigned sD = hf ? pk[5] : pk[7];
        const unsigned rA = (unsigned)__shfl_xor((int)sA, 32);
        const unsigned rB = (unsigned)__shfl_xor((int)sB, 32);
        const unsigned rC = (unsigned)__shfl_xor((int)sC, 32);
        const unsigned rD = (unsigned)__shfl_xor((int)sD, 32);

        // assemble P^T B-frags: B[k=hf*8+j][n=q=l31]
        int4 b1, b2;
        b1.x = hf ? (int)rA    : (int)pk[0];   // k rows 0-1 / 8-9
        b1.y = hf ? (int)rB    : (int)pk[1];   // 2-3 / 10-11
        b1.z = hf ? (int)pk[2] : (int)rA;      // 4-5 / 12-13
        b1.w = hf ? (int)pk[3] : (int)rB;      // 6-7 / 14-15
        b2.x = hf ? (int)rC    : (int)pk[4];
        b2.y = hf ? (int)rD    : (int)pk[5];
        b2.z = hf ? (int)pk[6] : (int)rC;
        b2.w = hf ? (int)pk[7] : (int)rD;
        const bf16x8 pB0 = __builtin_bit_cast(bf16x8, b1);
        const bf16x8 pB1 = __builtin_bit_cast(bf16x8, b2);

        Cacc = __builtin_amdgcn_mfma_f32_32x32x16_bf16(vA0, pB0, Cacc, 0, 0, 0);
        Cacc = __builtin_amdgcn_mfma_f32_32x32x16_bf16(vA1, pB1, Cacc, 0, 0, 0);
    }

    // Cacc = ctx^T[d][q]: lane holds col q=l31, rows d=(r&3)+8*(r>>2)+4*hf.
    // r=0..7 -> d in {0-3,8-11}+4*hf; r=8, hf=0 -> d=16 = l (maskbit row).
    #pragma unroll
    for (int r = 0; r < 8; ++r) {
        const int d = (r & 3) + 8*(r >> 2) + (hf ? 4 : 0);
        Cbuf[ks][l31][h*HD + d] = Cacc[r];
    }
    if (!hf) Lbuf[ks][h][l31] = Cacc[8];
    __syncthreads();

    // epilogue: thread = (q=tid>>4, 4 out cols); combine key-halves,
    // normalize per head, apply Wproj + bproj
    const int q   = tid >> 4;        // 0..31
    const int cbo = (tid & 15) * 4;  // 0..60
    float linv[NH];
    #pragma unroll
    for (int hh = 0; hh < NH; ++hh)
        linv[hh] = 1.0f / (Lbuf[0][hh][q] + Lbuf[1][hh][q]);

    float o0 = bproj[cbo], o1 = bproj[cbo+1], o2 = bproj[cbo+2], o3 = bproj[cbo+3];
    #pragma unroll
    for (int i = 0; i < 64; ++i) {
        const float cv = (Cbuf[0][q][i] + Cbuf[1][q][i]) * linv[i >> 4];
        const float4 wr = *(const float4*)(Wproj + i*DM + cbo);
        o0 += cv*wr.x; o1 += cv*wr.y; o2 += cv*wr.z; o3 += cv*wr.w;
    }
    float4 st; st.x = o0; st.y = o1; st.z = o2; st.w = o3;
    *(float4*)(out + ((size_t)b*TSEQ + qbase + q)*DM + cbo) = st;
}

extern "C" void kernel_launch(void* const* d_in, const int* in_sizes, int n_in,
                              void* d_out, int out_size, void* d_ws, size_t ws_size,
                              hipStream_t stream) {
    const float* x     = (const float*)d_in[0];
    const float* enc   = (const float*)d_in[1];
    const int*   mask  = (const int*)  d_in[2];
    const float* Wkv   = (const float*)d_in[3];
    const float* bkv   = (const float*)d_in[4];
    const float* Wq    = (const float*)d_in[5];
    const float* bq    = (const float*)d_in[6];
    const float* Wproj = (const float*)d_in[7];
    const float* bproj = (const float*)d_in[8];
    float* out = (float*)d_out;

    // ws: qhi,qlo,khi,klo 2MB each + vtt tiled (32 d-rows) 4MB = 12MB
    const size_t SZ = (size_t)BATCH*NH*TSEQ*HD;
    short* qhi = (short*)d_ws;
    short* qlo = qhi + SZ;
    short* khi = qlo + SZ;
    short* klo = khi + SZ;
    short* vtt = klo + SZ;   // BATCH*NH*32768 shorts

    proj_kernel<<<dim3(64, 12), dim3(256), 0, stream>>>(
        x, enc, Wkv, bkv, Wq, bq, mask, qhi, qlo, khi, klo, vtt);
    attn_kernel<<<dim3(512), dim3(512), 0, stream>>>(
        qhi, qlo, khi, klo, vtt, Wproj, bproj, out);
}

// Round 10
// 113.938 us; speedup vs baseline: 1.0049x; 1.0009x over previous
//
#include <hip/hip_runtime.h>
#include <hip/hip_bf16.h>
#include <math.h>

#define DM 64
#define NH 4
#define HD 16
#define BATCH 16
#define TSEQ 1024

typedef short bf16x8 __attribute__((ext_vector_type(8)));
typedef float f32x16 __attribute__((ext_vector_type(16)));

// fast RNE float->bf16 (finite inputs only: no NaN/inf path).
static __device__ inline unsigned bfround(float x) {
    unsigned u = __builtin_bit_cast(unsigned, x);
    return u + 0x7fffu + ((u >> 16) & 1u);     // rounded bits; bf16 = [31:16]
}
static __device__ inline short f2bf(float x) {
    return (short)(bfround(x) >> 16);
}
static __device__ inline float bf2f(short s) {
    unsigned u = ((unsigned)(unsigned short)s) << 16;
    return __builtin_bit_cast(float, u);
}
// pack two finite floats to bf16x2 (a->low, b->high)
static __device__ inline unsigned pack2bf(float a, float b) {
    return (bfround(a) >> 16) | (bfround(b) & 0xffff0000u);
}

// ---------------- Kernel 1: fused Q/K/V projections -> bf16 ---------------
// grid = (32 rowblocks of 512, 12 parts), 256 thr, thread = 2 rows x 16 cols
// (2-row blocking halves the LDS broadcast-read total per output).
// parts 0-3: q -> plain bf16 (scaled 0.25*log2e; NO lo-split — error enters
// S only via q rounding, ~0.6% in P, inside the absmax budget),
// parts 4-7: k -> hi/lo bf16 split, parts 8-11: v -> TILED
// vtt[b][h][kb][d][kw] with mask folded in (v *= mask, row d=16 = maskbit).
__global__ __launch_bounds__(256) void proj_kernel(
    const float* __restrict__ x, const float* __restrict__ enc,
    const float* __restrict__ Wkv, const float* __restrict__ bkv,
    const float* __restrict__ Wq,  const float* __restrict__ bq,
    const int* __restrict__ mask,
    short* __restrict__ qws,
    short* __restrict__ khi, short* __restrict__ klo,
    short* __restrict__ vtt)
{
    const int t = threadIdx.x;
    const int part = blockIdx.y;           // 0..11
    const int r0 = blockIdx.x * 512 + t;   // rows r0, r0+256 (same batch)

    const float* in; const float* W; const float* bias; int cb, ldw;
    if (part < 4)      { in = x;   W = Wq;  ldw = 64;  cb = part*16;          bias = bq;  }
    else if (part < 8) { in = enc; W = Wkv; ldw = 128; cb = (part-4)*16;      bias = bkv; }
    else               { in = enc; W = Wkv; ldw = 128; cb = 64 + (part-8)*16; bias = bkv; }

    const float4* row0 = (const float4*)(in + (size_t)r0 * 64);
    const float4* row1 = (const float4*)(in + (size_t)(r0 + 256) * 64);

    // first x chunk in flight before the staging barrier
    float4 xc[2][4];
    #pragma unroll
    for (int v4 = 0; v4 < 4; ++v4) { xc[0][v4] = row0[v4]; xc[1][v4] = row1[v4]; }

    __shared__ float wsl[64][16];
    #pragma unroll
    for (int idx = t; idx < 1024; idx += 256)
        wsl[idx >> 4][idx & 15] = W[(idx >> 4)*ldw + cb + (idx & 15)];
    __syncthreads();

    float acc[2][16];
    #pragma unroll
    for (int j = 0; j < 16; ++j) { float bj = bias[cb + j]; acc[0][j] = bj; acc[1][j] = bj; }

    for (int kc = 0; kc < 4; ++kc) {
        float4 xn[2][4];
        if (kc < 3) {
            #pragma unroll
            for (int v4 = 0; v4 < 4; ++v4) {
                xn[0][v4] = row0[(kc+1)*4 + v4];
                xn[1][v4] = row1[(kc+1)*4 + v4];
            }
        }
        #pragma unroll
        for (int i = 0; i < 16; ++i) {
            const int k = kc*16 + i;
            const float4 w0 = ((const float4*)&wsl[k][0])[0];
            const float4 w1 = ((const float4*)&wsl[k][0])[1];
            const float4 w2 = ((const float4*)&wsl[k][0])[2];
            const float4 w3 = ((const float4*)&wsl[k][0])[3];
            #pragma unroll
            for (int rr = 0; rr < 2; ++rr) {
                const float xv = ((const float*)&xc[rr][i >> 2])[i & 3];
                acc[rr][0]  += xv*w0.x; acc[rr][1]  += xv*w0.y; acc[rr][2]  += xv*w0.z; acc[rr][3]  += xv*w0.w;
                acc[rr][4]  += xv*w1.x; acc[rr][5]  += xv*w1.y; acc[rr][6]  += xv*w1.z; acc[rr][7]  += xv*w1.w;
                acc[rr][8]  += xv*w2.x; acc[rr][9]  += xv*w2.y; acc[rr][10] += xv*w2.z; acc[rr][11] += xv*w2.w;
                acc[rr][12] += xv*w3.x; acc[rr][13] += xv*w3.y; acc[rr][14] += xv*w3.z; acc[rr][15] += xv*w3.w;
            }
        }
        if (kc < 3) {
            #pragma unroll
            for (int v4 = 0; v4 < 4; ++v4) { xc[0][v4] = xn[0][v4]; xc[1][v4] = xn[1][v4]; }
        }
    }

    #pragma unroll
    for (int rr = 0; rr < 2; ++rr) {
        const int r = r0 + rr*256;
        const int b = r >> 10, trow = r & 1023;
        if (part < 4) {
            // q: plain bf16, fold 0.25*log2(e) so attn uses exp2 directly
            const float scale = 0.36067376022224085f;
            const int h = part;
            bf16x8 h0, h1;
            #pragma unroll
            for (int j = 0; j < 16; ++j) {
                short hb = f2bf(acc[rr][j] * scale);
                if (j < 8) h0[j] = hb; else h1[j-8] = hb;
            }
            size_t off = (((size_t)(b*NH + h))*TSEQ + trow)*HD;
            *(bf16x8*)(qws + off)     = h0;
            *(bf16x8*)(qws + off + 8) = h1;
        } else if (part < 8) {
            const int h = part - 4;
            bf16x8 h0, h1, l0, l1;
            #pragma unroll
            for (int j = 0; j < 16; ++j) {
                float vf = acc[rr][j];
                short hb = f2bf(vf);
                short lb = f2bf(vf - bf2f(hb));
                if (j < 8) { h0[j] = hb; l0[j] = lb; }
                else       { h1[j-8] = hb; l1[j-8] = lb; }
            }
            size_t off = (((size_t)(b*NH + h))*TSEQ + trow)*HD;
            *(bf16x8*)(khi + off)     = h0;
            *(bf16x8*)(khi + off + 8) = h1;
            *(bf16x8*)(klo + off)     = l0;
            *(bf16x8*)(klo + off + 8) = l1;
        } else {
            // vtt[b][h][kb=key>>5][d(0-15 data,16 maskbit,17-31 unused)][kw=key&31]
            const int h = part - 8;
            const float mb = (mask[b*TSEQ + trow] != 0) ? 1.0f : 0.0f;
            short* tile = vtt + ((size_t)(b*NH + h))*32768 + (size_t)(trow >> 5)*1024;
            const int kw = trow & 31;
            #pragma unroll
            for (int j = 0; j < 16; ++j)
                tile[j*32 + kw] = f2bf(acc[rr][j] * mb);
            tile[16*32 + kw] = (mb != 0.0f) ? (short)0x3F80 : (short)0;
        }
    }
}

// ---------------- Kernel 2: MFMA flash attention + Wproj epilogue ----------
// 1D grid 512, XCD-swizzled (b pinned to one XCD). 512 thr = 8 waves =
// (4 heads x 2 key-halves). Per 32-key step:
//   S^T[key][q] = 2x mfma(A=K hi/lo, B=Q)  (q plain bf16; P exits rows=keys)
//   p = exp2(S^T); fast bf16 pair-pack; 4x shfl_xor(,32) builds P^T frags
//   in-register; ctx^T += 2x mfma(A = V^T tiled, row16 = maskbit -> free l)
// Next-step K/V frags explicitly prefetched so their vmcnt waits overlap
// the exp2->pack->shfl dependency chain.
__global__ __launch_bounds__(512) void attn_kernel(
    const short* __restrict__ qws,
    const short* __restrict__ khi, const short* __restrict__ klo,
    const short* __restrict__ vtt,
    const float* __restrict__ Wproj, const float* __restrict__ bproj,
    float* __restrict__ out)
{
    const int tid  = threadIdx.x;
    const int lane = tid & 63;
    const int wid  = __builtin_amdgcn_readfirstlane(tid >> 6);  // 0..7
    const int h  = wid & 3;
    const int ks = wid >> 2;          // key half
    const int bid  = blockIdx.x;
    const int xcd  = bid & 7;
    const int slot = bid >> 3;                 // 0..63
    const int b    = (slot & 1) * 8 + xcd;     // batch -> fixed XCD
    const int qbase = (slot >> 1) * 32;        // q-tile 0..31
    const int l31 = lane & 31;
    const bool hf = (lane >> 5) != 0;

    __shared__ float Cbuf[2][32][67];    // [ks][q][4 heads x 16 d]; stride 67
    __shared__ float Lbuf[2][NH][32];

    // Q as MFMA B-operand: B[k=hf*8+j][n=q=l31]
    const size_t qoff = (((size_t)(b*NH + h))*TSEQ + qbase + l31)*HD + (hf ? 8 : 0);
    const bf16x8 qB = *(const bf16x8*)(qws + qoff);

    const short* khb = khi + (((size_t)(b*NH + h))*TSEQ + ks*512)*HD;
    const short* klb = klo + (((size_t)(b*NH + h))*TSEQ + ks*512)*HD;
    const short* vtb = vtt + ((size_t)(b*NH + h))*32768 + (size_t)ks*16384;

    f32x16 Cacc;
    #pragma unroll
    for (int i = 0; i < 16; ++i) Cacc[i] = 0.f;

    // step-0 frags
    bf16x8 kAh = *(const bf16x8*)(khb + (size_t)l31*HD + (hf ? 8 : 0));
    bf16x8 kAl = *(const bf16x8*)(klb + (size_t)l31*HD + (hf ? 8 : 0));
    bf16x8 vA0 = *(const bf16x8*)(vtb + l31*32 + (hf ? 8 : 0));
    bf16x8 vA1 = *(const bf16x8*)(vtb + l31*32 + 16 + (hf ? 8 : 0));

    for (int step = 0; step < 16; ++step) {
        // prefetch next step's frags (step 15 reloads itself: harmless)
        const int nko = ((step < 15) ? step + 1 : 15) * 32;
        const short* ntile = vtb + (size_t)(nko >> 5) * 1024;
        const bf16x8 nkAh = *(const bf16x8*)(khb + (size_t)(nko + l31)*HD + (hf ? 8 : 0));
        const bf16x8 nkAl = *(const bf16x8*)(klb + (size_t)(nko + l31)*HD + (hf ? 8 : 0));
        const bf16x8 nvA0 = *(const bf16x8*)(ntile + l31*32 + (hf ? 8 : 0));
        const bf16x8 nvA1 = *(const bf16x8*)(ntile + l31*32 + 16 + (hf ? 8 : 0));

        f32x16 S;   // S^T: C-layout lane holds col q=l31, rows=keys
        #pragma unroll
        for (int i = 0; i < 16; ++i) S[i] = 0.f;
        S = __builtin_amdgcn_mfma_f32_32x32x16_bf16(kAh, qB, S, 0, 0, 0);
        S = __builtin_amdgcn_mfma_f32_32x32x16_bf16(kAl, qB, S, 0, 0, 0);

        float p[16];
        #pragma unroll
        for (int i = 0; i < 16; ++i) p[i] = __builtin_amdgcn_exp2f(S[i]);

        // pack pairs (rows 2i,2i+1) to bf16x2 — fast finite-only RNE
        unsigned pk[8];
        #pragma unroll
        for (int i = 0; i < 8; ++i) pk[i] = pack2bf(p[2*i], p[2*i+1]);

        // exchange across lane^32:
        //   hf=0 lane needs partner pk0,pk1 (frag1) and pk4,pk5 (frag2)
        //   hf=1 lane needs partner pk2,pk3 (frag1) and pk6,pk7 (frag2)
        const unsigned sA = hf ? pk[0] : pk[2];
        const unsigned sB = hf ? pk[1] : pk[3];
        const unsigned sC = hf ? pk[4] : pk[6];
        const unsigned sD = hf ? pk[5] : pk[7];
        const unsigned rA = (unsigned)__shfl_xor((int)sA, 32);
        const unsigned rB = (unsigned)__shfl_xor((int)sB, 32);
        const unsigned rC = (unsigned)__shfl_xor((int)sC, 32);
        const unsigned rD = (unsigned)__shfl_xor((int)sD, 32);

        // assemble P^T B-frags: B[k=hf*8+j][n=q=l31]
        int4 b1, b2;
        b1.x = hf ? (int)rA    : (int)pk[0];   // k rows 0-1 / 8-9
        b1.y = hf ? (int)rB    : (int)pk[1];   // 2-3 / 10-11
        b1.z = hf ? (int)pk[2] : (int)rA;      // 4-5 / 12-13
        b1.w = hf ? (int)pk[3] : (int)rB;      // 6-7 / 14-15
        b2.x = hf ? (int)rC    : (int)pk[4];
        b2.y = hf ? (int)rD    : (int)pk[5];
        b2.z = hf ? (int)pk[6] : (int)rC;
        b2.w = hf ? (int)pk[7] : (int)rD;
        const bf16x8 pB0 = __builtin_bit_cast(bf16x8, b1);
        const bf16x8 pB1 = __builtin_bit_cast(bf16x8, b2);

        Cacc = __builtin_amdgcn_mfma_f32_32x32x16_bf16(vA0, pB0, Cacc, 0, 0, 0);
        Cacc = __builtin_amdgcn_mfma_f32_32x32x16_bf16(vA1, pB1, Cacc, 0, 0, 0);

        kAh = nkAh; kAl = nkAl; vA0 = nvA0; vA1 = nvA1;
    }

    // Cacc = ctx^T[d][q]: lane holds col q=l31, rows d=(r&3)+8*(r>>2)+4*hf.
    // r=0..7 -> d in {0-3,8-11}+4*hf; r=8, hf=0 -> d=16 = l (maskbit row).
    #pragma unroll
    for (int r = 0; r < 8; ++r) {
        const int d = (r & 3) + 8*(r >> 2) + (hf ? 4 : 0);
        Cbuf[ks][l31][h*HD + d] = Cacc[r];
    }
    if (!hf) Lbuf[ks][h][l31] = Cacc[8];
    __syncthreads();

    // epilogue: thread = (q=tid>>4, 4 out cols); combine key-halves,
    // normalize per head, apply Wproj + bproj
    const int q   = tid >> 4;        // 0..31
    const int cbo = (tid & 15) * 4;  // 0..60
    float linv[NH];
    #pragma unroll
    for (int hh = 0; hh < NH; ++hh)
        linv[hh] = 1.0f / (Lbuf[0][hh][q] + Lbuf[1][hh][q]);

    float o0 = bproj[cbo], o1 = bproj[cbo+1], o2 = bproj[cbo+2], o3 = bproj[cbo+3];
    #pragma unroll
    for (int i = 0; i < 64; ++i) {
        const float cv = (Cbuf[0][q][i] + Cbuf[1][q][i]) * linv[i >> 4];
        const float4 wr = *(const float4*)(Wproj + i*DM + cbo);
        o0 += cv*wr.x; o1 += cv*wr.y; o2 += cv*wr.z; o3 += cv*wr.w;
    }
    float4 st; st.x = o0; st.y = o1; st.z = o2; st.w = o3;
    *(float4*)(out + ((size_t)b*TSEQ + qbase + q)*DM + cbo) = st;
}

extern "C" void kernel_launch(void* const* d_in, const int* in_sizes, int n_in,
                              void* d_out, int out_size, void* d_ws, size_t ws_size,
                              hipStream_t stream) {
    const float* x     = (const float*)d_in[0];
    const float* enc   = (const float*)d_in[1];
    const int*   mask  = (const int*)  d_in[2];
    const float* Wkv   = (const float*)d_in[3];
    const float* bkv   = (const float*)d_in[4];
    const float* Wq    = (const float*)d_in[5];
    const float* bq    = (const float*)d_in[6];
    const float* Wproj = (const float*)d_in[7];
    const float* bproj = (const float*)d_in[8];
    float* out = (float*)d_out;

    // ws: qws, khi, klo 2MB each + vtt tiled (32 d-rows) 4MB = 10MB
    const size_t SZ = (size_t)BATCH*NH*TSEQ*HD;
    short* qws = (short*)d_ws;
    short* khi = qws + SZ;
    short* klo = khi + SZ;
    short* vtt = klo + SZ;   // BATCH*NH*32768 shorts

    proj_kernel<<<dim3(32, 12), dim3(256), 0, stream>>>(
        x, enc, Wkv, bkv, Wq, bq, mask, qws, khi, klo, vtt);
    attn_kernel<<<dim3(512), dim3(512), 0, stream>>>(
        qws, khi, klo, vtt, Wproj, bproj, out);
}